// Round 12
// baseline (82717.932 us; speedup 1.0000x reference)
//
#include <hip/hip_runtime.h>
#include <stdint.h>

#define T_STEPS 4096
#define BATCH 32
#define HID 512
#define BLK_THREADS 1024    // 16 waves = 4/SIMD; reg budget 512/lane

// Round 12: ZERO inter-block communication. One block per batch; the whole
// 2048x512 W_hh lives in ONE CU's register file as int8 (1 MB = 256 dwords
// per lane; fits the 512-reg/lane budget at 4 waves/SIMD — rounds 1-2's
// "rematerialization" was the 128-reg cap of __launch_bounds__(512,4), not
// a pin failure). v_dot4_i32_i8 = 4 MACs/instr. All per-step state moves
// through LDS + __syncthreads only: no polls, no cache-coherence games, no
// unbounded loops, no workspace. Rounds 2-11 showed every cross-CU protocol
// costs ~3.4 us/step of sync tax + metastable 3x slow modes; this design
// makes both structurally impossible.
//
// Quantization: per-row scale sc_r = rowmax/127 (w ~ q_w*sc_r); h fixed
// scale 127 (|h|<1 strictly, tanh*sigmoid). gate = dot * rowmax/16129.
// Expected absmax ~0.01-0.03 vs threshold 0.085.

__device__ inline int sdot4(uint32_t a, uint32_t b, int c) {
#if __has_builtin(__builtin_amdgcn_sdot4)
  return __builtin_amdgcn_sdot4((int)a, (int)b, c, false);
#else
  int d;
  asm("v_dot4_i32_i8 %0, %1, %2, %3" : "=v"(d) : "v"(a), "v"(b), "v"(c));
  return d;
#endif
}

__device__ inline float sigf(float x) { return 1.0f / (1.0f + __expf(-x)); }
__device__ inline float tanh_fast(float x) {
  float a = fabsf(x);
  float e = __expf(-2.0f * a);
  float r = (1.0f - e) / (1.0f + e);
  return copysignf(r, x);
}

__global__ __launch_bounds__(BLK_THREADS)
void lstm_onecu(const float* __restrict__ x0,
                const float* __restrict__ W_ih,
                const float* __restrict__ W_hh,
                const float* __restrict__ b_ih,
                const float* __restrict__ b_hh,
                const float* __restrict__ W_lin,
                const float* __restrict__ b_lin,
                float* __restrict__ y)
{
  __shared__ float x0_lds[T_STEPS];     // 16 KB: this batch's x0 column
  __shared__ float ylds[T_STEPS];       // 16 KB: per-step y partials
  __shared__ float gsum[4 * HID];       // 8 KB: gate sums, indexed by row
  __shared__ uint32_t hq[HID / 4];      // 512 B: h quantized i8, packed x4

  const int tid = threadIdx.x;
  const int b = blockIdx.x;             // batch — blocks fully independent

  // ---- one-time: load + quantize 2 rows of W_hh into registers ----
  // Lane owns rows r0 = tid (gates i/f) and r1 = tid + 1024 (gates g/o).
  uint32_t wq0[128], wq1[128];
  float scl0, scl1;                      // rowmax / (127*127)
  {
    const float4* p0 = (const float4*)(W_hh + (size_t)tid * HID);
    const float4* p1 = (const float4*)(W_hh + (size_t)(tid + 1024) * HID);
    float m0 = 1e-20f, m1 = 1e-20f;
#pragma unroll
    for (int k = 0; k < 128; ++k) {
      float4 a = p0[k];
      m0 = fmaxf(m0, fmaxf(fmaxf(fabsf(a.x), fabsf(a.y)),
                           fmaxf(fabsf(a.z), fabsf(a.w))));
      float4 c = p1[k];
      m1 = fmaxf(m1, fmaxf(fmaxf(fabsf(c.x), fabsf(c.y)),
                           fmaxf(fabsf(c.z), fabsf(c.w))));
    }
    const float i0 = 127.0f / m0, i1 = 127.0f / m1;
    scl0 = m0 / 16129.0f;
    scl1 = m1 / 16129.0f;
#pragma unroll
    for (int k = 0; k < 128; ++k) {
      float4 a = p0[k];
      int q0 = (int)rintf(a.x * i0), q1 = (int)rintf(a.y * i0);
      int q2 = (int)rintf(a.z * i0), q3 = (int)rintf(a.w * i0);
      wq0[k] = (uint32_t)((q0 & 0xff) | ((q1 & 0xff) << 8) |
                          ((q2 & 0xff) << 16) | ((q3 & 0xff) << 24));
      float4 c = p1[k];
      int s0 = (int)rintf(c.x * i1), s1 = (int)rintf(c.y * i1);
      int s2 = (int)rintf(c.z * i1), s3 = (int)rintf(c.w * i1);
      wq1[k] = (uint32_t)((s0 & 0xff) | ((s1 & 0xff) << 8) |
                          ((s2 & 0xff) << 16) | ((s3 & 0xff) << 24));
    }
    // Pin: forces materialization; with the 512-reg budget these stay
    // resident for the whole t-loop (AGPR spill-over is register-speed on
    // gfx950's unified file — never memory).
#pragma unroll
    for (int k = 0; k < 128; ++k) asm("" : "+v"(wq0[k]), "+v"(wq1[k]));
  }

  // ---- one-time: x0 column, y partials, h0 = 0 ----
  for (int i = tid; i < T_STEPS; i += BLK_THREADS) {
    x0_lds[i] = x0[i * BATCH + b];
    ylds[i] = 0.f;
  }
  if (tid < HID / 4) hq[tid] = 0u;

  // ---- activation-lane constants (tid < 512: unit u = tid) ----
  float c_state = 0.f;
  float wih_[4] = {0.f, 0.f, 0.f, 0.f}, bs_[4] = {0.f, 0.f, 0.f, 0.f};
  float wlin_u = 0.f;
  if (tid < HID) {
#pragma unroll
    for (int j = 0; j < 4; ++j) {
      int R = j * HID + tid;
      wih_[j] = W_ih[R];
      bs_[j] = b_ih[R] + b_hh[R];
    }
    wlin_u = W_lin[tid];
  }
  const float blin = b_lin[0];

  __syncthreads();

  for (int t = 0; t < T_STEPS; ++t) {
    // ---- matvec: 2 full rows per lane, h broadcast from LDS ----
    int acc0 = 0, acc1 = 0;
    const uint4* hp = (const uint4*)hq;
#pragma unroll
    for (int q = 0; q < 32; ++q) {
      uint4 h4 = hp[q];
      const int k = 4 * q;
      acc0 = sdot4(wq0[k + 0], h4.x, acc0); acc1 = sdot4(wq1[k + 0], h4.x, acc1);
      acc0 = sdot4(wq0[k + 1], h4.y, acc0); acc1 = sdot4(wq1[k + 1], h4.y, acc1);
      acc0 = sdot4(wq0[k + 2], h4.z, acc0); acc1 = sdot4(wq1[k + 2], h4.z, acc1);
      acc0 = sdot4(wq0[k + 3], h4.w, acc0); acc1 = sdot4(wq1[k + 3], h4.w, acc1);
    }
    gsum[tid]        = (float)acc0 * scl0;   // row r0 (stride-1: no conflicts)
    gsum[tid + 1024] = (float)acc1 * scl1;   // row r1
    __syncthreads();                          // sums ready

    // ---- activation (tid < 512; unit u = tid) ----
    if (tid < HID) {
      const float xv = x0_lds[t];
      float gi = gsum[tid]             + xv * wih_[0] + bs_[0];
      float gf = gsum[tid + HID]       + xv * wih_[1] + bs_[1];
      float gg = gsum[tid + 2 * HID]   + xv * wih_[2] + bs_[2];
      float go = gsum[tid + 3 * HID]   + xv * wih_[3] + bs_[3];
      float si = sigf(gi), sf = sigf(gf), tg = tanh_fast(gg), so = sigf(go);
      c_state = sf * c_state + si * tg;
      float h = so * tanh_fast(c_state);

      // quantize h -> i8 (|h| < 1 strictly => |q| <= 127), pack 4 lanes
      int hb = (int)rintf(h * 127.0f);
      int v1 = __shfl_down(hb, 1, 64);
      int v2 = __shfl_down(hb, 2, 64);
      int v3 = __shfl_down(hb, 3, 64);
      if ((tid & 3) == 0) {
        hq[tid >> 2] = (uint32_t)((hb & 0xff) | ((v1 & 0xff) << 8) |
                                  ((v2 & 0xff) << 16) | ((v3 & 0xff) << 24));
      }

      // y partial: fold 64 units per wave, one LDS atomic per wave
      float p = wlin_u * h;
#pragma unroll
      for (int m = 32; m >= 1; m >>= 1) p += __shfl_xor(p, m, 64);
      if ((tid & 63) == 0) atomicAdd(&ylds[t], p);
    }
    __syncthreads();                          // hq[t+1] ready
  }

  // ---- drain: sole owner of this batch's y column — plain stores ----
  for (int i = tid; i < T_STEPS; i += BLK_THREADS) {
    y[i * BATCH + b] = ylds[i] + blin + x0_lds[i];
  }
}

extern "C" void kernel_launch(void* const* d_in, const int* in_sizes, int n_in,
                              void* d_out, int out_size, void* d_ws, size_t ws_size,
                              hipStream_t stream) {
  const float* x0    = (const float*)d_in[0];
  const float* W_ih  = (const float*)d_in[1];
  const float* W_hh  = (const float*)d_in[2];
  const float* b_ih  = (const float*)d_in[3];
  const float* b_hh  = (const float*)d_in[4];
  const float* W_lin = (const float*)d_in[5];
  const float* b_lin = (const float*)d_in[6];
  float* y = (float*)d_out;

  // No workspace, no memsets: each block fully owns + overwrites its batch
  // column of y; all state is in-kernel.
  hipLaunchKernelGGL(lstm_onecu, dim3(BATCH), dim3(BLK_THREADS), 0, stream,
                     x0, W_ih, W_hh, b_ih, b_hh, W_lin, b_lin, y);
}